// Round 6
// baseline (214.296 us; speedup 1.0000x reference)
//
#include <hip/hip_runtime.h>
#include <hip/hip_bf16.h>

typedef _Float16 f16;
typedef _Float16 f16x8 __attribute__((ext_vector_type(8)));
typedef float f32x4 __attribute__((ext_vector_type(4)));

#define NB 32
#define NM 64
#define NC 36
#define NEG_INF_F (-1e10f)

__device__ __forceinline__ void stage16(const f16* g, f16* l) {
    __builtin_amdgcn_global_load_lds((const __attribute__((address_space(1))) void*)g,
                                     (__attribute__((address_space(3))) void*)l, 16, 0, 0);
}

// ---------------- conversion kernels ----------------

__global__ __launch_bounds__(256) void cvt_dense(const float* __restrict__ in,
                                                 f16* __restrict__ out, int n) {
    int i = blockIdx.x * 256 + threadIdx.x;
    if (i < n) out[i] = (f16)in[i];
}

// out: rows x 1024 (zero-padded), in: rows x K
__global__ __launch_bounds__(256) void cvt_pad1024(const float* __restrict__ in,
                                                   f16* __restrict__ out, int rows, int K) {
    int i = blockIdx.x * 256 + threadIdx.x;
    int r = i >> 10, k = i & 1023;
    if (r < rows) out[i] = (k < K) ? (f16)in[r * K + k] : (f16)0.f;
}

// w: K x 512 (row-major f32) -> wt: 512 x Kp (f16, k-major, zero-padded)
__global__ __launch_bounds__(256) void cvt_transpose(const float* __restrict__ w,
                                                     f16* __restrict__ wt, int K, int Kp) {
    int i = blockIdx.x * 256 + threadIdx.x;
    int n = i & 511;
    int k = i >> 9;
    if (k < Kp) wt[n * Kp + k] = (k < K) ? (f16)w[k * 512 + n] : (f16)0.f;
}

// ---------------- generic f16 MFMA GEMM: out = act(A @ Wt^T + bias) ----------------
__global__ __launch_bounds__(256) void gemm16(const f16* __restrict__ A,
                                              const f16* __restrict__ Wt,
                                              const float* __restrict__ bias,
                                              f16* __restrict__ out,
                                              int K, int N, int relu) {
    int lane = threadIdx.x & 63;
    int w = threadIdx.x >> 6;
    int wr = w >> 1, wc = w & 1;
    int m0 = blockIdx.x * 64 + wr * 32;
    int n0 = blockIdx.y * 64 + wc * 32;
    int rl = lane & 15, kg = lane >> 4;

    f32x4 acc[2][2] = {};

    const f16* a0p = A + (m0 + rl) * K + kg * 8;
    const f16* a1p = a0p + 16 * K;
    const f16* b0p = Wt + (n0 + rl) * K + kg * 8;
    const f16* b1p = b0p + 16 * K;

    for (int k0 = 0; k0 < K; k0 += 32) {
        f16x8 a0 = *(const f16x8*)(a0p + k0);
        f16x8 a1 = *(const f16x8*)(a1p + k0);
        f16x8 b0 = *(const f16x8*)(b0p + k0);
        f16x8 b1 = *(const f16x8*)(b1p + k0);
        acc[0][0] = __builtin_amdgcn_mfma_f32_16x16x32_f16(a0, b0, acc[0][0], 0, 0, 0);
        acc[0][1] = __builtin_amdgcn_mfma_f32_16x16x32_f16(a0, b1, acc[0][1], 0, 0, 0);
        acc[1][0] = __builtin_amdgcn_mfma_f32_16x16x32_f16(a1, b0, acc[1][0], 0, 0, 0);
        acc[1][1] = __builtin_amdgcn_mfma_f32_16x16x32_f16(a1, b1, acc[1][1], 0, 0, 0);
    }

    #pragma unroll
    for (int fi = 0; fi < 2; fi++)
        #pragma unroll
        for (int fj = 0; fj < 2; fj++) {
            int col = n0 + fj * 16 + rl;
            float bv = bias[col];
            #pragma unroll
            for (int r = 0; r < 4; r++) {
                int row = m0 + fi * 16 + kg * 4 + r;
                float v = acc[fi][fj][r] + bv;
                if (relu) v = fmaxf(v, 0.f);
                out[row * N + col] = (f16)v;
            }
        }
}

// ---------------- main fused kernel ----------------
// grid: (2 jt, 18 cp, 32 b), block 256 (4 waves). Wave w: j0 = jt*256 + w*64, both c's.
// aw1t j-slice (256 rows) is LDS-staged per 32-k chunk, double-buffered:
//   LDS layout [kg 0..3][row 0..255][8 f16]; wave w stages kg=w via global_load_lds
//   (linear LDS dest = wave base + lane*16; per-lane global src — G21-compliant).
// B-fragments come from ds_read_b128 (<=2-way bank aliasing = free);
// men/vis stay global (all 4 waves read identical addrs in lockstep -> L1 hits).
__global__ __launch_bounds__(256, 2) void attn_main(const f16* __restrict__ men,
                                                    const f16* __restrict__ vis,
                                                    const f16* __restrict__ aw1t,
                                                    const float* __restrict__ ab1,
                                                    const float* __restrict__ aw2,
                                                    float* __restrict__ out_acc) {
    __shared__ f16 smem[2][8192];  // 2 x 16KB

    int lane = threadIdx.x & 63;
    int w = threadIdx.x >> 6;
    int b = blockIdx.z, cp = blockIdx.y, jt = blockIdx.x;
    int c0 = cp * 2;
    int j0blk = jt * 256;
    int j0 = j0blk + w * 64;
    int rl = lane & 15, kg = lane >> 4;

    const f16* menb  = men + (b * NM + rl) * 512 + kg * 8;
    const f16* visb0 = vis + (b * NC + c0) * 512 + kg * 8;
    // staging src for wave w, iter it, lane l: row = it*64+l (block-rel), cols k0 + w*8 .. +7
    const f16* stg = aw1t + (j0blk + lane) * 512 + w * 8;

    f32x4 acc0[4][4] = {};
    f32x4 acc1[4][4] = {};

    // prologue: stage chunk 0 into buf 0
    #pragma unroll
    for (int it = 0; it < 4; it++)
        stage16(stg + it * 64 * 512, &smem[0][w * 2048 + it * 512]);
    __syncthreads();  // compiler emits vmcnt(0) drain before s_barrier

    for (int s = 0; s < 16; s++) {
        int k0 = s * 32;
        int cur = s & 1;

        // issue next chunk's staging first: latency hides under this step's MFMAs
        if (s < 15) {
            #pragma unroll
            for (int it = 0; it < 4; it++)
                stage16(stg + (k0 + 32) + it * 64 * 512, &smem[cur ^ 1][w * 2048 + it * 512]);
        }

        f16x8 vv0 = *(const f16x8*)(visb0 + k0);
        f16x8 vv1 = *(const f16x8*)(visb0 + 512 + k0);
        f16x8 mm[4], bf[4];
        #pragma unroll
        for (int fi = 0; fi < 4; fi++)
            mm[fi] = *(const f16x8*)(menb + fi * 16 * 512 + k0);
        #pragma unroll
        for (int fj = 0; fj < 4; fj++)
            bf[fj] = *(const f16x8*)&smem[cur][kg * 2048 + (w * 64 + fj * 16 + rl) * 8];

        #pragma unroll
        for (int fi = 0; fi < 4; fi++) {
            f16x8 a0 = mm[fi] * vv0;   // packed f16 multiply
            #pragma unroll
            for (int fj = 0; fj < 4; fj++)
                acc0[fi][fj] = __builtin_amdgcn_mfma_f32_16x16x32_f16(a0, bf[fj], acc0[fi][fj], 0, 0, 0);
        }
        #pragma unroll
        for (int fi = 0; fi < 4; fi++) {
            f16x8 a1 = mm[fi] * vv1;
            #pragma unroll
            for (int fj = 0; fj < 4; fj++)
                acc1[fi][fj] = __builtin_amdgcn_mfma_f32_16x16x32_f16(a1, bf[fj], acc1[fi][fj], 0, 0, 0);
        }

        if (s < 15)
            __syncthreads();  // drains staging vmcnt + protects buf reuse
    }

    // epilogue (fp32): part[m] = sum_j relu(acc + ab1[j]) * aw2[j], for both c
    float ab1v[4], aw2v[4];
    #pragma unroll
    for (int fj = 0; fj < 4; fj++) {
        int j = j0 + fj * 16 + rl;
        ab1v[fj] = ab1[j];
        aw2v[fj] = aw2[j];
    }
    float part0[4][4], part1[4][4];
    #pragma unroll
    for (int fi = 0; fi < 4; fi++)
        #pragma unroll
        for (int r = 0; r < 4; r++) {
            float s0 = 0.f, s1 = 0.f;
            #pragma unroll
            for (int fj = 0; fj < 4; fj++) {
                float v0 = fmaxf(acc0[fi][fj][r] + ab1v[fj], 0.f);
                float v1 = fmaxf(acc1[fi][fj][r] + ab1v[fj], 0.f);
                s0 += v0 * aw2v[fj];
                s1 += v1 * aw2v[fj];
            }
            part0[fi][r] = s0;
            part1[fi][r] = s1;
        }
    #pragma unroll
    for (int mask = 1; mask < 16; mask <<= 1)
        #pragma unroll
        for (int fi = 0; fi < 4; fi++)
            #pragma unroll
            for (int r = 0; r < 4; r++) {
                part0[fi][r] += __shfl_xor(part0[fi][r], mask);
                part1[fi][r] += __shfl_xor(part1[fi][r], mask);
            }

    // lane (rl, kg) owns (fi = rl>>2, r = rl&3) -> m = (rl>>2)*16 + kg*4 + (rl&3)
    float myv0 = 0.f, myv1 = 0.f;
    #pragma unroll
    for (int fi = 0; fi < 4; fi++)
        #pragma unroll
        for (int r = 0; r < 4; r++) {
            bool sel = (rl == fi * 4 + r);
            myv0 = sel ? part0[fi][r] : myv0;
            myv1 = sel ? part1[fi][r] : myv1;
        }
    int m = (rl >> 2) * 16 + kg * 4 + (rl & 3);
    atomicAdd(&out_acc[(b * NM + m) * NC + c0], myv0);
    atomicAdd(&out_acc[(b * NM + m) * NC + c0 + 1], myv1);
}

// ---------------- post-process: + ab2, masks, NEG_INF ----------------
__global__ __launch_bounds__(256) void postproc(float* __restrict__ out,
                                                const float* __restrict__ mm,
                                                const float* __restrict__ cm,
                                                const float* __restrict__ ab2) {
    int i = blockIdx.x * 256 + threadIdx.x;  // < 73728
    int b = i / (NM * NC);
    int rest = i - b * (NM * NC);
    int m = rest / NC, c = rest - m * NC;
    float t = (out[i] + ab2[0]) * mm[b * NM + m] * cm[b * NC + c];
    out[i] = (t != 0.f) ? t : NEG_INF_F;
}

extern "C" void kernel_launch(void* const* d_in, const int* in_sizes, int n_in,
                              void* d_out, int out_size, void* d_ws, size_t ws_size,
                              hipStream_t stream) {
    const float* ME  = (const float*)d_in[0];   // (32,64,1024)
    const float* CL  = (const float*)d_in[1];   // (32,36,1000)
    const float* MM  = (const float*)d_in[2];   // (32,64)
    const float* CM  = (const float*)d_in[3];   // (32,36)
    const float* VW1 = (const float*)d_in[4];   // (1000,512)
    const float* VB1 = (const float*)d_in[5];
    const float* VW2 = (const float*)d_in[6];   // (512,512)
    const float* VB2 = (const float*)d_in[7];
    const float* MW1 = (const float*)d_in[8];   // (1024,512)
    const float* MB1 = (const float*)d_in[9];
    const float* MW2 = (const float*)d_in[10];  // (512,512)
    const float* MB2 = (const float*)d_in[11];
    const float* AW1 = (const float*)d_in[12];  // (512,512)
    const float* AB1 = (const float*)d_in[13];
    const float* AW2 = (const float*)d_in[14];  // (512,1)
    const float* AB2 = (const float*)d_in[15];  // (1,)
    float* out = (float*)d_out;

    char* ws = (char*)d_ws;
    f16* me_h  = (f16*)ws; ws += (size_t)2048 * 1024 * 2;
    f16* cl_h  = (f16*)ws; ws += (size_t)1152 * 1024 * 2;
    f16* mw1t  = (f16*)ws; ws += (size_t)512 * 1024 * 2;
    f16* mw2t  = (f16*)ws; ws += (size_t)512 * 512 * 2;
    f16* vw1t  = (f16*)ws; ws += (size_t)512 * 1024 * 2;
    f16* vw2t  = (f16*)ws; ws += (size_t)512 * 512 * 2;
    f16* aw1t  = (f16*)ws; ws += (size_t)512 * 512 * 2;
    f16* men1  = (f16*)ws; ws += (size_t)2048 * 512 * 2;
    f16* menh  = (f16*)ws; ws += (size_t)2048 * 512 * 2;
    f16* vis1  = (f16*)ws; ws += (size_t)1152 * 512 * 2;
    f16* vish  = (f16*)ws; ws += (size_t)1152 * 512 * 2;

    hipMemsetAsync(d_out, 0, (size_t)73728 * sizeof(float), stream);

    cvt_dense<<<2048 * 1024 / 256, 256, 0, stream>>>(ME, me_h, 2048 * 1024);
    cvt_pad1024<<<1152 * 1024 / 256, 256, 0, stream>>>(CL, cl_h, 1152, 1000);
    cvt_transpose<<<512 * 1024 / 256, 256, 0, stream>>>(MW1, mw1t, 1024, 1024);
    cvt_transpose<<<512 * 512 / 256, 256, 0, stream>>>(MW2, mw2t, 512, 512);
    cvt_transpose<<<512 * 1024 / 256, 256, 0, stream>>>(VW1, vw1t, 1000, 1024);
    cvt_transpose<<<512 * 512 / 256, 256, 0, stream>>>(VW2, vw2t, 512, 512);
    cvt_transpose<<<512 * 512 / 256, 256, 0, stream>>>(AW1, aw1t, 512, 512);

    gemm16<<<dim3(2048 / 64, 512 / 64), 256, 0, stream>>>(me_h, mw1t, MB1, men1, 1024, 512, 1);
    gemm16<<<dim3(2048 / 64, 512 / 64), 256, 0, stream>>>(men1, mw2t, MB2, menh, 512, 512, 0);
    gemm16<<<dim3(1152 / 64, 512 / 64), 256, 0, stream>>>(cl_h, vw1t, VB1, vis1, 1024, 512, 1);
    gemm16<<<dim3(1152 / 64, 512 / 64), 256, 0, stream>>>(vis1, vw2t, VB2, vish, 512, 512, 0);

    attn_main<<<dim3(2, 18, 32), 256, 0, stream>>>(menh, vish, aw1t, AB1, AW2, out);

    postproc<<<73728 / 256, 256, 0, stream>>>(out, MM, CM, AB2);
}

// Round 7
// 172.835 us; speedup vs baseline: 1.2399x; 1.2399x over previous
//
#include <hip/hip_runtime.h>

typedef _Float16 f16;
typedef _Float16 f16x8 __attribute__((ext_vector_type(8)));
typedef float f32x4 __attribute__((ext_vector_type(4)));
typedef float fl4 __attribute__((ext_vector_type(4)));

#define NEG_INF_F (-1e10f)

__device__ __forceinline__ void stage16(const f16* g, f16* l) {
    __builtin_amdgcn_global_load_lds((const __attribute__((address_space(1))) void*)g,
                                     (__attribute__((address_space(3))) void*)l, 16, 0, 0);
}

// ---------------- all 5 weight transposes in one kernel (writes coalesced, k-fast) ----
// seg0: mw1t 512x1024 <- MW1(1024,512); seg1: vw1t 512x1024 <- VW1(1000,512) zero-pad
// seg2: mw2t 512x512; seg3: vw2t; seg4: aw1t
__global__ __launch_bounds__(256) void wxpose(const float* __restrict__ mw1,
                                              const float* __restrict__ vw1,
                                              const float* __restrict__ mw2,
                                              const float* __restrict__ vw2,
                                              const float* __restrict__ aw1,
                                              f16* __restrict__ mw1t, f16* __restrict__ vw1t,
                                              f16* __restrict__ mw2t, f16* __restrict__ vw2t,
                                              f16* __restrict__ aw1t) {
    int i = blockIdx.x * 256 + threadIdx.x;
    if (i < 1048576) {
        int seg = i >> 19;
        int j = i & 524287;
        int k = j & 1023, n = j >> 10;
        if (seg == 0) mw1t[n * 1024 + k] = (f16)mw1[k * 512 + n];
        else          vw1t[n * 1024 + k] = (k < 1000) ? (f16)vw1[k * 512 + n] : (f16)0.f;
    } else {
        int j = i - 1048576;
        int seg = j >> 18;
        int r = j & 262143;
        int k = r & 511, n = r >> 9;
        const float* src = (seg == 0) ? mw2 : (seg == 1) ? vw2 : aw1;
        f16* dst = (seg == 0) ? mw2t : (seg == 1) ? vw2t : aw1t;
        dst[n * 512 + k] = (f16)src[k * 512 + n];
    }
}

// class_labels (1152,1000) f32 -> (1152,1024) f16 zero-padded
__global__ __launch_bounds__(256) void cvt_pad1024(const float* __restrict__ in,
                                                   f16* __restrict__ out) {
    int i = blockIdx.x * 256 + threadIdx.x;
    int r = i >> 10, k = i & 1023;
    out[i] = (k < 1000) ? (f16)in[r * 1000 + k] : (f16)0.f;
}

__device__ __forceinline__ f16x8 cvt8(const float* p) {
    fl4 x = *(const fl4*)p;
    fl4 y = *(const fl4*)(p + 4);
    f16x8 r;
    #pragma unroll
    for (int e = 0; e < 4; e++) { r[e] = (f16)x[e]; r[4 + e] = (f16)y[e]; }
    return r;
}

// ---------------- stage 1: men1 = relu(ME@mw1t + mb1)  [A=f32, rows 2048, bx<32]
//                            vis1 = relu(cl_h@vw1t + vb1) [A=f16, rows 1152, bx>=32]
__global__ __launch_bounds__(256) void gemm_s1(const float* __restrict__ Af,
                                               const f16* __restrict__ Ah,
                                               const f16* __restrict__ Wm, const f16* __restrict__ Wv,
                                               const float* __restrict__ bm, const float* __restrict__ bv,
                                               f16* __restrict__ om, f16* __restrict__ ov) {
    int lane = threadIdx.x & 63, w = threadIdx.x >> 6;
    int wr = w >> 1, wc = w & 1;
    int rl = lane & 15, kg = lane >> 4;
    bool isv = blockIdx.x >= 32;
    int mb = isv ? blockIdx.x - 32 : blockIdx.x;
    const f16* Wt = isv ? Wv : Wm;
    const float* bias = isv ? bv : bm;
    f16* out = isv ? ov : om;
    int m0 = mb * 64 + wr * 32, n0 = blockIdx.y * 64 + wc * 32;

    f32x4 acc[2][2] = {};
    const f16* b0p = Wt + (n0 + rl) * 1024 + kg * 8;
    const f16* b1p = b0p + 16 * 1024;
    const float* af0 = Af + (m0 + rl) * 1024 + kg * 8;
    const float* af1 = af0 + 16 * 1024;
    const f16* ah0 = Ah + (m0 + rl) * 1024 + kg * 8;
    const f16* ah1 = ah0 + 16 * 1024;

    for (int k0 = 0; k0 < 1024; k0 += 32) {
        f16x8 a0, a1;
        if (!isv) { a0 = cvt8(af0 + k0); a1 = cvt8(af1 + k0); }
        else      { a0 = *(const f16x8*)(ah0 + k0); a1 = *(const f16x8*)(ah1 + k0); }
        f16x8 b0 = *(const f16x8*)(b0p + k0);
        f16x8 b1 = *(const f16x8*)(b1p + k0);
        acc[0][0] = __builtin_amdgcn_mfma_f32_16x16x32_f16(a0, b0, acc[0][0], 0, 0, 0);
        acc[0][1] = __builtin_amdgcn_mfma_f32_16x16x32_f16(a0, b1, acc[0][1], 0, 0, 0);
        acc[1][0] = __builtin_amdgcn_mfma_f32_16x16x32_f16(a1, b0, acc[1][0], 0, 0, 0);
        acc[1][1] = __builtin_amdgcn_mfma_f32_16x16x32_f16(a1, b1, acc[1][1], 0, 0, 0);
    }
    #pragma unroll
    for (int fi = 0; fi < 2; fi++)
        #pragma unroll
        for (int fj = 0; fj < 2; fj++) {
            int col = n0 + fj * 16 + rl;
            float bv2 = bias[col];
            #pragma unroll
            for (int r = 0; r < 4; r++) {
                int row = m0 + fi * 16 + kg * 4 + r;
                out[row * 512 + col] = (f16)fmaxf(acc[fi][fj][r] + bv2, 0.f);
            }
        }
}

// ---------------- stage 2: menh = men1@mw2t + mb2; vish = vis1@vw2t + vb2 (K=512, no relu)
__global__ __launch_bounds__(256) void gemm_s2(const f16* __restrict__ Am,
                                               const f16* __restrict__ Av,
                                               const f16* __restrict__ Wm, const f16* __restrict__ Wv,
                                               const float* __restrict__ bm, const float* __restrict__ bv,
                                               f16* __restrict__ om, f16* __restrict__ ov) {
    int lane = threadIdx.x & 63, w = threadIdx.x >> 6;
    int wr = w >> 1, wc = w & 1;
    int rl = lane & 15, kg = lane >> 4;
    bool isv = blockIdx.x >= 32;
    int mb = isv ? blockIdx.x - 32 : blockIdx.x;
    const f16* A = isv ? Av : Am;
    const f16* Wt = isv ? Wv : Wm;
    const float* bias = isv ? bv : bm;
    f16* out = isv ? ov : om;
    int m0 = mb * 64 + wr * 32, n0 = blockIdx.y * 64 + wc * 32;

    f32x4 acc[2][2] = {};
    const f16* a0p = A + (m0 + rl) * 512 + kg * 8;
    const f16* a1p = a0p + 16 * 512;
    const f16* b0p = Wt + (n0 + rl) * 512 + kg * 8;
    const f16* b1p = b0p + 16 * 512;

    for (int k0 = 0; k0 < 512; k0 += 32) {
        f16x8 a0 = *(const f16x8*)(a0p + k0);
        f16x8 a1 = *(const f16x8*)(a1p + k0);
        f16x8 b0 = *(const f16x8*)(b0p + k0);
        f16x8 b1 = *(const f16x8*)(b1p + k0);
        acc[0][0] = __builtin_amdgcn_mfma_f32_16x16x32_f16(a0, b0, acc[0][0], 0, 0, 0);
        acc[0][1] = __builtin_amdgcn_mfma_f32_16x16x32_f16(a0, b1, acc[0][1], 0, 0, 0);
        acc[1][0] = __builtin_amdgcn_mfma_f32_16x16x32_f16(a1, b0, acc[1][0], 0, 0, 0);
        acc[1][1] = __builtin_amdgcn_mfma_f32_16x16x32_f16(a1, b1, acc[1][1], 0, 0, 0);
    }
    #pragma unroll
    for (int fi = 0; fi < 2; fi++)
        #pragma unroll
        for (int fj = 0; fj < 2; fj++) {
            int col = n0 + fj * 16 + rl;
            float bv2 = bias[col];
            #pragma unroll
            for (int r = 0; r < 4; r++) {
                int row = m0 + fi * 16 + kg * 4 + r;
                out[row * 512 + col] = (f16)(acc[fi][fj][r] + bv2);
            }
        }
}

// ---------------- fused attention ----------------
// grid (18 cp, 32 b), block 512 (8 waves). Wave w: j in [w*64, w*64+64), both c of pair.
// aw1t staged ONCE per block in 64KB k-chunks (dbuf), XOR-swizzled (unit ^= j&7) so
// ds_read_b128 of B-fragments is conflict-free; linear LDS dest + pre-swizzled global
// src (G21). Block LDS-reduce over 8 waves' j-partials -> direct masked store.
__global__ __launch_bounds__(512, 2) void attn_fused(const f16* __restrict__ men,
                                                     const f16* __restrict__ vis,
                                                     const f16* __restrict__ aw1t,
                                                     const float* __restrict__ ab1,
                                                     const float* __restrict__ aw2,
                                                     const float* __restrict__ ab2,
                                                     const float* __restrict__ maskm,
                                                     const float* __restrict__ maskc,
                                                     float* __restrict__ out) {
    __shared__ f16 buf[2][32768];    // 2 x 64KB: [j 0..511][unit 0..7][8 f16], swizzled
    __shared__ float red[8][2][64];  // 4KB wave-partial reduction

    int t = threadIdx.x;
    int lane = t & 63, w = t >> 6;
    int cp = blockIdx.x, b = blockIdx.y;
    int c0 = cp * 2;
    int rl = lane & 15, kg = lane >> 4;
    int j0 = w * 64;

    // staging: round r, thread t covers linear dest bytes r*8192 + t*16:
    //   j = r*64 + (t>>3), linear unit u = t&7, holds logical k8 = u ^ (j&7)
    int uu = (t & 7) ^ ((t >> 3) & 7);
    const f16* stg_base = aw1t + (t >> 3) * 512 + uu * 8;  // + r*64*512 + s*64

    const f16* menb = men + (b * 64 + rl) * 512 + kg * 8;
    const f16* visb = vis + (b * 36 + c0) * 512 + kg * 8;

    f32x4 acc0[4][4] = {}, acc1[4][4] = {};

    // prologue: stage chunk 0
    #pragma unroll
    for (int r = 0; r < 8; r++)
        stage16(stg_base + r * 64 * 512, &buf[0][r * 4096 + w * 512]);
    __syncthreads();

    for (int s = 0; s < 8; s++) {
        int cur = s & 1;
        if (s < 7) {  // issue next chunk before compute; drained by the barrier below
            #pragma unroll
            for (int r = 0; r < 8; r++)
                stage16(stg_base + r * 64 * 512 + (s + 1) * 64, &buf[cur ^ 1][r * 4096 + w * 512]);
        }
        #pragma unroll
        for (int ks = 0; ks < 2; ks++) {
            int k = s * 64 + ks * 32;
            f16x8 vv0 = *(const f16x8*)(visb + k);
            f16x8 vv1 = *(const f16x8*)(visb + 512 + k);
            f16x8 mm[4], bf[4];
            #pragma unroll
            for (int fi = 0; fi < 4; fi++)
                mm[fi] = *(const f16x8*)(menb + fi * 16 * 512 + k);
            #pragma unroll
            for (int fj = 0; fj < 4; fj++) {
                int j = j0 + fj * 16 + rl;
                int un = (ks * 4 + kg) ^ (j & 7);
                bf[fj] = *(const f16x8*)&buf[cur][j * 64 + un * 8];
            }
            #pragma unroll
            for (int fi = 0; fi < 4; fi++) {
                f16x8 a0 = mm[fi] * vv0;
                #pragma unroll
                for (int fj = 0; fj < 4; fj++)
                    acc0[fi][fj] = __builtin_amdgcn_mfma_f32_16x16x32_f16(a0, bf[fj], acc0[fi][fj], 0, 0, 0);
            }
            #pragma unroll
            for (int fi = 0; fi < 4; fi++) {
                f16x8 a1 = mm[fi] * vv1;
                #pragma unroll
                for (int fj = 0; fj < 4; fj++)
                    acc1[fi][fj] = __builtin_amdgcn_mfma_f32_16x16x32_f16(a1, bf[fj], acc1[fi][fj], 0, 0, 0);
            }
        }
        __syncthreads();
    }

    // per-wave epilogue (fp32): partial over this wave's 64 j
    float ab1v[4], aw2v[4];
    #pragma unroll
    for (int fj = 0; fj < 4; fj++) {
        int j = j0 + fj * 16 + rl;
        ab1v[fj] = ab1[j];
        aw2v[fj] = aw2[j];
    }
    float part0[4][4], part1[4][4];
    #pragma unroll
    for (int fi = 0; fi < 4; fi++)
        #pragma unroll
        for (int r = 0; r < 4; r++) {
            float s0 = 0.f, s1 = 0.f;
            #pragma unroll
            for (int fj = 0; fj < 4; fj++) {
                s0 += fmaxf(acc0[fi][fj][r] + ab1v[fj], 0.f) * aw2v[fj];
                s1 += fmaxf(acc1[fi][fj][r] + ab1v[fj], 0.f) * aw2v[fj];
            }
            part0[fi][r] = s0;
            part1[fi][r] = s1;
        }
    #pragma unroll
    for (int mask = 1; mask < 16; mask <<= 1)
        #pragma unroll
        for (int fi = 0; fi < 4; fi++)
            #pragma unroll
            for (int r = 0; r < 4; r++) {
                part0[fi][r] += __shfl_xor(part0[fi][r], mask);
                part1[fi][r] += __shfl_xor(part1[fi][r], mask);
            }
    float myv0 = 0.f, myv1 = 0.f;
    #pragma unroll
    for (int fi = 0; fi < 4; fi++)
        #pragma unroll
        for (int r = 0; r < 4; r++) {
            bool sel = (rl == fi * 4 + r);
            myv0 = sel ? part0[fi][r] : myv0;
            myv1 = sel ? part1[fi][r] : myv1;
        }
    int m = (rl >> 2) * 16 + kg * 4 + (rl & 3);
    red[w][0][m] = myv0;
    red[w][1][m] = myv1;
    __syncthreads();

    if (t < 128) {
        int ci = t >> 6, m2 = t & 63;
        float s = 0.f;
        #pragma unroll
        for (int ww = 0; ww < 8; ww++) s += red[ww][ci][m2];
        int c = c0 + ci;
        float v = (s + ab2[0]) * maskm[b * 64 + m2] * maskc[b * 36 + c];
        out[(b * 64 + m2) * 36 + c] = (v != 0.f) ? v : NEG_INF_F;
    }
}

extern "C" void kernel_launch(void* const* d_in, const int* in_sizes, int n_in,
                              void* d_out, int out_size, void* d_ws, size_t ws_size,
                              hipStream_t stream) {
    const float* ME  = (const float*)d_in[0];   // (32,64,1024)
    const float* CL  = (const float*)d_in[1];   // (32,36,1000)
    const float* MM  = (const float*)d_in[2];   // (32,64)
    const float* CM  = (const float*)d_in[3];   // (32,36)
    const float* VW1 = (const float*)d_in[4];   // (1000,512)
    const float* VB1 = (const float*)d_in[5];
    const float* VW2 = (const float*)d_in[6];   // (512,512)
    const float* VB2 = (const float*)d_in[7];
    const float* MW1 = (const float*)d_in[8];   // (1024,512)
    const float* MB1 = (const float*)d_in[9];
    const float* MW2 = (const float*)d_in[10];  // (512,512)
    const float* MB2 = (const float*)d_in[11];
    const float* AW1 = (const float*)d_in[12];  // (512,512)
    const float* AB1 = (const float*)d_in[13];
    const float* AW2 = (const float*)d_in[14];  // (512,1)
    const float* AB2 = (const float*)d_in[15];  // (1,)
    float* out = (float*)d_out;

    char* ws = (char*)d_ws;
    f16* cl_h  = (f16*)ws; ws += (size_t)1152 * 1024 * 2;
    f16* mw1t  = (f16*)ws; ws += (size_t)512 * 1024 * 2;
    f16* vw1t  = (f16*)ws; ws += (size_t)512 * 1024 * 2;
    f16* mw2t  = (f16*)ws; ws += (size_t)512 * 512 * 2;
    f16* vw2t  = (f16*)ws; ws += (size_t)512 * 512 * 2;
    f16* aw1t  = (f16*)ws; ws += (size_t)512 * 512 * 2;
    f16* men1  = (f16*)ws; ws += (size_t)2048 * 512 * 2;
    f16* menh  = (f16*)ws; ws += (size_t)2048 * 512 * 2;
    f16* vis1  = (f16*)ws; ws += (size_t)1152 * 512 * 2;
    f16* vish  = (f16*)ws; ws += (size_t)1152 * 512 * 2;

    wxpose<<<7168, 256, 0, stream>>>(MW1, VW1, MW2, VW2, AW1, mw1t, vw1t, mw2t, vw2t, aw1t);
    cvt_pad1024<<<1152 * 1024 / 256, 256, 0, stream>>>(CL, cl_h);
    gemm_s1<<<dim3(50, 8), 256, 0, stream>>>(ME, cl_h, mw1t, vw1t, MB1, VB1, men1, vis1);
    gemm_s2<<<dim3(50, 8), 256, 0, stream>>>(men1, vis1, mw2t, vw2t, MB2, VB2, menh, vish);
    attn_fused<<<dim3(18, 32), 512, 0, stream>>>(menh, vish, aw1t, AB1, AW2, AB2, MM, CM, out);
}